// Round 4
// baseline (76.103 us; speedup 1.0000x reference)
//
#include <hip/hip_runtime.h>
#include <math.h>

// MeshfreeKANNet: out[m] = sum_n phi(m,n) * w[n]
//   phi = windowed+normalized softplus(KAN(diff/radius)), cubic window r=0.06
//   orphan rows (phi_sum < 1e-14): exp-weighted 8-NN fallback.
// R4: spatial binning. radius 0.06 < cell 1/16, so the 3x3 cell neighborhood
// covers the support (~72 candidates vs 2048). Prepass sorts nodes by cell
// into d_ws (SoA bx/by/bw + cell_start[257]); main kernel runs one wave per
// row over 3 contiguous candidate ranges.

#define RADIUS 0.06f
#define INV_RADIUS (1.0f / 0.06f)
#define R2C (0.06f * 0.06f)
#define INV_H (4.0f / 3.0f)   // 1/h, h = 0.75
#define BINS 16
#define NCELL (BINS * BINS)

__device__ __forceinline__ float hatf(float x, float g) {
    return fmaxf(1.0f - fabsf(x - g) * INV_H, 0.0f);
}

// softplus(KAN(dx/r, dy/r)) * cubic_window(sqrt(d2)/r)
__device__ __forceinline__ float kan_phi(float dx, float dy, float d2,
                                         const float* __restrict__ s_w1a,
                                         const float* __restrict__ s_w1b,
                                         const float* __restrict__ s_w2) {
    const float u = dx * INV_RADIUS;
    const float v = dy * INV_RADIUS;
    float b0[5], b1[5];
    #pragma unroll
    for (int i = 0; i < 5; ++i) {
        const float g = -1.5f + 0.75f * (float)i;
        b0[i] = hatf(u, g);
        b1[i] = hatf(v, g);
    }
    float o = 0.0f;
    #pragma unroll
    for (int j = 0; j < 8; ++j) {
        float hj = 0.0f;
        #pragma unroll
        for (int i = 0; i < 5; ++i)
            hj += b0[i] * s_w1a[j * 5 + i] + b1[i] * s_w1b[j * 5 + i];
        #pragma unroll
        for (int g = 0; g < 5; ++g) {
            const float gv = -1.5f + 0.75f * (float)g;
            o += hatf(hj, gv) * s_w2[j * 5 + g];
        }
    }
    // stable softplus (matches jax.nn.softplus in fp32)
    const float sp = fmaxf(o, 0.0f) + log1pf(expf(-fabsf(o)));
    // cubic window on q = d/r
    const float q = sqrtf(d2) * INV_RADIUS;
    float win;
    if (q <= 0.5f) win = 2.0f / 3.0f - 4.0f * q * q + 4.0f * q * q * q;
    else           win = 4.0f / 3.0f - 4.0f * q + 4.0f * q * q
                         - (4.0f / 3.0f) * q * q * q;
    return sp * win;
}

// ---- prepass: cell-sort nodes. 1 block x 1024 threads. ----
__global__ __launch_bounds__(1024) void bin_kernel(
    const float* __restrict__ nodes, const float* __restrict__ w,
    float* __restrict__ bx, float* __restrict__ by, float* __restrict__ bw,
    int* __restrict__ cell_start, int N)
{
    const int t = threadIdx.x;
    const int lane = t & 63, wv = t >> 6;
    const float2* __restrict__ nodes2 = (const float2*)nodes;
    __shared__ int hist[NCELL];
    __shared__ int ofs[NCELL];
    __shared__ int wsum[4];

    if (t < NCELL) hist[t] = 0;
    __syncthreads();

    for (int i = t; i < N; i += 1024) {
        const float2 p = nodes2[i];
        const int cx = min(max((int)(p.x * (float)BINS), 0), BINS - 1);
        const int cy = min(max((int)(p.y * (float)BINS), 0), BINS - 1);
        atomicAdd(&hist[cy * BINS + cx], 1);
    }
    __syncthreads();

    // exclusive scan of hist[256] on threads 0..255 (4 waves)
    int v = 0, inc = 0;
    if (t < NCELL) {
        v = hist[t];
        inc = v;
        #pragma unroll
        for (int off = 1; off < 64; off <<= 1) {
            const int u = __shfl_up(inc, off);
            if (lane >= off) inc += u;
        }
        if (lane == 63) wsum[wv] = inc;
    }
    __syncthreads();
    if (t < NCELL) {
        int base = 0;
        for (int k = 0; k < wv; ++k) base += wsum[k];
        const int excl = base + inc - v;
        ofs[t] = excl;
        cell_start[t] = excl;
        if (t == 0) cell_start[NCELL] = N;
    }
    __syncthreads();

    for (int i = t; i < N; i += 1024) {
        const float2 p = nodes2[i];
        const int cx = min(max((int)(p.x * (float)BINS), 0), BINS - 1);
        const int cy = min(max((int)(p.y * (float)BINS), 0), BINS - 1);
        const int pos = atomicAdd(&ofs[cy * BINS + cx], 1);
        bx[pos] = p.x;
        by[pos] = p.y;
        bw[pos] = w[i];
    }
}

// ---- main: one wave per row, 3x3-cell candidate ranges. ----
__global__ __launch_bounds__(256) void meshfree_kan_kernel(
    const float* __restrict__ x,
    const float* __restrict__ bx, const float* __restrict__ by,
    const float* __restrict__ bw, const int* __restrict__ cell_start,
    const float* __restrict__ w1a, const float* __restrict__ w1b,
    const float* __restrict__ w2,
    float* __restrict__ out, int M, int N)
{
    const int t = threadIdx.x;
    const int lane = t & 63, wave = t >> 6;

    __shared__ float s_w1a[40], s_w1b[40], s_w2[40];
    if (t < 40)       s_w1a[t]      = w1a[t];
    else if (t < 80)  s_w1b[t - 40] = w1b[t - 40];
    else if (t < 120) s_w2[t - 80]  = w2[t - 80];
    __syncthreads();

    const int m = blockIdx.x * 4 + wave;
    if (m >= M) return;

    const float x0 = x[2 * m], x1 = x[2 * m + 1];
    const int cx = min(max((int)(x0 * (float)BINS), 0), BINS - 1);
    const int cy = min(max((int)(x1 * (float)BINS), 0), BINS - 1);

    float s1 = 0.0f, s2 = 0.0f;
    #pragma unroll
    for (int dy = -1; dy <= 1; ++dy) {
        const int ry = cy + dy;
        if ((unsigned)ry >= (unsigned)BINS) continue;
        const int clo = ry * BINS + max(cx - 1, 0);
        const int chi = ry * BINS + min(cx + 1, BINS - 1);
        const int lo = cell_start[clo];
        const int hi = cell_start[chi + 1];
        for (int base = lo; base < hi; base += 64) {
            const int i = base + lane;
            const bool valid = i < hi;
            const float px = valid ? bx[i] : 1e15f;
            const float py = valid ? by[i] : 1e15f;
            const float dxv = x0 - px;
            const float dyv = x1 - py;
            const float d2 = fmaf(dxv, dxv, dyv * dyv);
            const bool active = d2 <= R2C;
            if (__ballot(active)) {
                if (active) {
                    const float pw = kan_phi(dxv, dyv, d2,
                                             s_w1a, s_w1b, s_w2);
                    s1 += pw;
                    s2 += pw * bw[i];
                }
            }
        }
    }

    // wave butterfly reduction (all lanes end with the sums)
    #pragma unroll
    for (int off = 32; off; off >>= 1) {
        s1 += __shfl_xor(s1, off);
        s2 += __shfl_xor(s2, off);
    }

    if (s1 < 1e-14f) {
        // ---- orphan: exp-weighted 8-NN over ALL binned nodes (rare) ----
        // Selection by d^2 with binned-index tiebreak: the final weighted sum
        // is order-independent and exact distance ties are measure-zero, so
        // this matches the reference top_k semantics.
        const float alpha = (float)(20.0 / 0.06);
        const int KITER = (N + 63) >> 6;
        unsigned long long last = 0ull;
        float accw = 0.0f, accwv = 0.0f;
        const int kk = (N < 8) ? N : 8;
        for (int sel = 0; sel < kk; ++sel) {
            unsigned long long best = ~0ull;
            for (int k = 0; k < KITER; ++k) {
                const int i = lane + (k << 6);
                const float px = (i < N) ? bx[i] : 1e15f;
                const float py = (i < N) ? by[i] : 1e15f;
                const float dxv = x0 - px;
                const float dyv = x1 - py;
                const float d2 = fmaf(dxv, dxv, dyv * dyv);
                const unsigned long long key =
                    ((unsigned long long)__float_as_uint(d2) << 32) |
                    (unsigned)i;
                if (key > last && key < best) best = key;
            }
            #pragma unroll
            for (int off = 32; off; off >>= 1) {
                const unsigned lo = (unsigned)best;
                const unsigned hi = (unsigned)(best >> 32);
                const unsigned olo = __shfl_xor(lo, off);
                const unsigned ohi = __shfl_xor(hi, off);
                const unsigned long long other =
                    ((unsigned long long)ohi << 32) | olo;
                if (other < best) best = other;
            }
            last = best;
            const float dk = sqrtf(__uint_as_float((unsigned)(best >> 32)));
            const int idx = (int)(best & 0xffffffffu);
            const float wk = expf(-alpha * dk);
            accw += wk;
            accwv += wk * bw[idx];
        }
        if (lane == 0) out[m] = accwv / (accw + 1e-18f);
    } else {
        if (lane == 0) out[m] = s2 / (s1 + 1e-12f);
    }
}

extern "C" void kernel_launch(void* const* d_in, const int* in_sizes, int n_in,
                              void* d_out, int out_size, void* d_ws, size_t ws_size,
                              hipStream_t stream) {
    const float* x     = (const float*)d_in[0];
    const float* nodes = (const float*)d_in[1];
    const float* w     = (const float*)d_in[2];
    const float* w1a   = (const float*)d_in[3];
    const float* w1b   = (const float*)d_in[4];
    const float* w2    = (const float*)d_in[5];
    const int M = in_sizes[0] / 2;
    const int N = in_sizes[1] / 2;
    float* out = (float*)d_out;

    // d_ws layout: bx[N] | by[N] | bw[N] | cell_start[NCELL+1]
    float* bx = (float*)d_ws;
    float* by = bx + N;
    float* bw = by + N;
    int* cell_start = (int*)(bw + N);

    bin_kernel<<<dim3(1), dim3(1024), 0, stream>>>(
        nodes, w, bx, by, bw, cell_start, N);

    const int nblocks = (M + 3) / 4;
    meshfree_kan_kernel<<<dim3(nblocks), dim3(256), 0, stream>>>(
        x, bx, by, bw, cell_start, w1a, w1b, w2, out, M, N);
}